// Round 1
// baseline (150.988 us; speedup 1.0000x reference)
//
#include <hip/hip_runtime.h>
#include <stdint.h>

#define NBITS 57
#define RPB   256   // rows per block

__global__ __launch_bounds__(256) void lzc57_kernel(const uint32_t* __restrict__ X,
                                                    float* __restrict__ out,
                                                    int nrows) {
    __shared__ uint32_t s_in[RPB * NBITS];   // 58368 B
    __shared__ float    s_out[RPB * 6];      // 6144 B
    const int tid  = threadIdx.x;
    const int row0 = blockIdx.x * RPB;
    const int rows = min(RPB, nrows - row0);
    const int nwords = rows * NBITS;

    // ---- stage input chunk (contiguous, coalesced uint4) ----
    const uint32_t* src = X + (size_t)row0 * NBITS;
    const int n4 = nwords >> 2;              // chunk base is 16B-aligned (256*57*4 % 16 == 0)
    const uint4* src4 = (const uint4*)src;
    uint4* dst4 = (uint4*)s_in;
    for (int i = tid; i < n4; i += RPB) dst4[i] = src4[i];
    for (int i = (n4 << 2) + tid; i < nwords; i += RPB) s_in[i] = src[i];
    __syncthreads();

    // ---- per-row LZC (one thread per row) ----
    if (tid < rows) {
        const uint32_t* r = &s_in[tid * NBITS];   // stride 57: gcd(57,32)=1 -> conflict-free
        unsigned long long m = 0ull;
        #pragma unroll
        for (int i = 0; i < NBITS; ++i)
            m |= (unsigned long long)(r[i] != 0u) << i;
        const int lzc = m ? (__ffsll(m) - 1) : 57;
        #pragma unroll
        for (int j = 0; j < 6; ++j)
            s_out[tid * 6 + j] = (float)((lzc >> (5 - j)) & 1);
    }
    __syncthreads();

    // ---- coalesced float4 store of staged output ----
    float* dstf = out + (size_t)row0 * 6;
    const int nout = rows * 6;
    const int no4 = nout >> 2;
    const float4* s4 = (const float4*)s_out;
    float4* o4 = (float4*)dstf;
    for (int i = tid; i < no4; i += RPB) o4[i] = s4[i];
    for (int i = (no4 << 2) + tid; i < nout; i += RPB) dstf[i] = s_out[i];
}

extern "C" void kernel_launch(void* const* d_in, const int* in_sizes, int n_in,
                              void* d_out, int out_size, void* d_ws, size_t ws_size,
                              hipStream_t stream) {
    const uint32_t* X = (const uint32_t*)d_in[0];
    float* out = (float*)d_out;
    const int nrows = in_sizes[0] / NBITS;
    const int blocks = (nrows + RPB - 1) / RPB;
    lzc57_kernel<<<blocks, RPB, 0, stream>>>(X, out, nrows);
}

// Round 2
// 94.496 us; speedup vs baseline: 1.5978x; 1.5978x over previous
//
#include <hip/hip_runtime.h>
#include <stdint.h>

#define NBITS 57
#define RPB   256   // rows per block

typedef const __attribute__((address_space(1))) void gvoid_t;
typedef __attribute__((address_space(3))) void       lvoid_t;

__global__ __launch_bounds__(256) void lzc57_kernel(const uint32_t* __restrict__ X,
                                                    float* __restrict__ out,
                                                    int nrows) {
    __shared__ uint32_t s_in[RPB * NBITS];   // 58368 B, linear (global_load_lds dest)
    __shared__ float    s_out[RPB * 6];      // 6144 B
    const int tid  = threadIdx.x;
    const int row0 = blockIdx.x * RPB;
    const int rows = min(RPB, nrows - row0);

    const uint32_t* src = X + (size_t)row0 * NBITS;

    if (rows == RPB) {
        // Full block: 256*57/4 = 3648 uint4 = 14 rounds x 256 + 64 tail.
        // Async direct-to-LDS, 14-15 outstanding 1KB loads per wave.
        const int wave = tid >> 6;
        const int lane = tid & 63;
        const uint4* src4 = (const uint4*)src;
        #pragma unroll
        for (int r = 0; r < 14; ++r) {
            const int idx = r * 256 + wave * 64;     // uint4 index of this wave's base
            __builtin_amdgcn_global_load_lds(
                (gvoid_t*)(src4 + idx + lane),       // per-lane global source
                (lvoid_t*)(s_in + (size_t)idx * 4),  // wave-uniform LDS base (+lane*16 in HW)
                16, 0, 0);
        }
        if (wave == 0) {                             // tail: 64 uint4
            const int idx = 14 * 256;
            __builtin_amdgcn_global_load_lds(
                (gvoid_t*)(src4 + idx + lane),
                (lvoid_t*)(s_in + (size_t)idx * 4),
                16, 0, 0);
        }
    } else {
        // Partial last block: simple bounds-checked staging (runs once per grid).
        const int nwords = rows * NBITS;
        for (int i = tid; i < nwords; i += RPB) s_in[i] = src[i];
    }
    __syncthreads();   // compiler emits s_waitcnt vmcnt(0) before s_barrier

    // ---- per-row LZC (one thread per row) ----
    if (tid < rows) {
        const uint32_t* r = &s_in[tid * NBITS];   // stride 57: gcd(57,32)=1 -> conflict-free
        // input words are exactly 0x00000000 (0.0f) or 0x3F800000 (1.0f): bit 29 discriminates
        uint32_t mlo = 0u, mhi = 0u;
        #pragma unroll
        for (int i = 0; i < 32; ++i)
            mlo |= ((r[i] >> 29) & 1u) << i;
        #pragma unroll
        for (int i = 32; i < NBITS; ++i)
            mhi |= ((r[i] >> 29) & 1u) << (i - 32);
        const int lzc = mlo ? (__ffs(mlo) - 1) : (mhi ? (31 + __ffs(mhi)) : 57);
        #pragma unroll
        for (int j = 0; j < 6; ++j)
            s_out[tid * 6 + j] = (float)((lzc >> (5 - j)) & 1);
    }
    __syncthreads();

    // ---- coalesced float4 store of staged output ----
    float* dstf = out + (size_t)row0 * 6;
    const int nout = rows * 6;                // full block: 1536 (divisible by 4)
    const int no4 = nout >> 2;
    const float4* s4 = (const float4*)s_out;
    float4* o4 = (float4*)dstf;
    for (int i = tid; i < no4; i += RPB) o4[i] = s4[i];
    for (int i = (no4 << 2) + tid; i < nout; i += RPB) dstf[i] = s_out[i];
}

extern "C" void kernel_launch(void* const* d_in, const int* in_sizes, int n_in,
                              void* d_out, int out_size, void* d_ws, size_t ws_size,
                              hipStream_t stream) {
    const uint32_t* X = (const uint32_t*)d_in[0];
    float* out = (float*)d_out;
    const int nrows = in_sizes[0] / NBITS;
    const int blocks = (nrows + RPB - 1) / RPB;
    lzc57_kernel<<<blocks, RPB, 0, stream>>>(X, out, nrows);
}